// Round 1
// baseline (80.550 us; speedup 1.0000x reference)
//
#include <hip/hip_runtime.h>
#include <hip/hip_bf16.h>

typedef __attribute__((ext_vector_type(8))) short bf16x8;
typedef __attribute__((ext_vector_type(4))) float f32x4;

constexpr int BQ  = 4096;          // batch per view
constexpr int DD  = 128;           // dim
constexpr int N2  = 2 * BQ;        // 8192 rows
constexpr int NCH = 16;            // column chunks -> grid (64, 16) = 1024 blocks
constexpr int CHW = N2 / NCH;      // 512 cols per block
// exp(s / 0.5) = exp2(s * 2/ln2)
constexpr float SCALE = 2.8853900817779268f;

static __device__ __forceinline__ ushort f2bf(float f) {
    unsigned u = __builtin_bit_cast(unsigned, f);
    u += 0x7FFFu + ((u >> 16) & 1u);     // round-to-nearest-even
    return (ushort)(u >> 16);
}

// ---- kernel 1: fp32 [out_1; out_2] -> bf16 [8192][128] -------------------
__global__ void convert_k(const float* __restrict__ a, const float* __restrict__ b,
                          ushort* __restrict__ ob)
{
    int i = blockIdx.x * blockDim.x + threadIdx.x;   // 262144 threads, 4 floats each
    int base = i * 4;
    const float* src = (base < BQ * DD) ? (a + base) : (b + (base - BQ * DD));
    float4 v = *reinterpret_cast<const float4*>(src);
    ushort4 p = make_ushort4(f2bf(v.x), f2bf(v.y), f2bf(v.z), f2bf(v.w));
    *reinterpret_cast<ushort4*>(ob + base) = p;
}

// ---- kernel 2: fused Gram + exp + mask + row sums ------------------------
// block = 256 threads = 4 waves laid out 2x2; wave tile = 64x64; block tile
// 128 rows x 512 cols (4 col-tiles of 128). A frags live in registers; B
// frags read straight from L2 (whole matrix = 2MB, fits per-XCD L2).
__global__ __launch_bounds__(256, 2) void simloss_main(
        const ushort* __restrict__ ob, const int* __restrict__ tgt,
        float* __restrict__ pf, float* __restrict__ png)
{
    const int lane = threadIdx.x & 63;
    const int wid  = threadIdx.x >> 6;
    const int wr   = wid >> 1;            // wave row 0..1
    const int wc   = wid & 1;             // wave col 0..1
    const int l15  = lane & 15;
    const int l4   = lane >> 4;
    const int rt   = blockIdx.x;          // 0..63 row tile
    const int ch   = blockIdx.y;          // 0..15 col chunk

    const int rowbase = rt * 128 + wr * 64;

    // A fragments (rows of out), held for the whole block: 16 x bf16x8
    bf16x8 af[4][4];
    {
        const ushort* ap = ob + (rowbase + l15) * DD + l4 * 8;
#pragma unroll
        for (int m = 0; m < 4; ++m)
#pragma unroll
            for (int kk = 0; kk < 4; ++kk)
                af[m][kk] = *reinterpret_cast<const bf16x8*>(ap + m * 16 * DD + kk * 32);
    }

    // per-lane row targets (sentinel for -1 so it never matches)
    int tr[4][4];
#pragma unroll
    for (int m = 0; m < 4; ++m)
#pragma unroll
        for (int r = 0; r < 4; ++r) {
            int row = rowbase + m * 16 + l4 * 4 + r;
            int t = tgt[row & (BQ - 1)];
            tr[m][r] = (t == -1) ? (int)0x80000000 : t;
        }

    const int dl = l4 * 4 - l15;                 // per-lane diag key
    const int rmodbase = rowbase & (BQ - 1);     // wave-uniform (64-row strip never straddles 4096)

    float fs[4][4] = {};   // row sums (all cols)
    float ns[4][4] = {};   // row sums (kept cols)

#pragma unroll 1
    for (int ct = 0; ct < CHW / 128; ++ct) {
        const int cb = ch * CHW + ct * 128 + wc * 64;   // wave's col base
        const int cmodb = cb & (BQ - 1);
        const int sdiff = cmodb - rmodbase;

        f32x4 acc[4][4] = {};
#pragma unroll
        for (int kk = 0; kk < 4; ++kk) {
            bf16x8 bf[4];
#pragma unroll
            for (int n = 0; n < 4; ++n)
                bf[n] = *reinterpret_cast<const bf16x8*>(
                    ob + (cb + n * 16 + l15) * DD + kk * 32 + l4 * 8);
#pragma unroll
            for (int m = 0; m < 4; ++m)
#pragma unroll
                for (int n = 0; n < 4; ++n)
                    acc[m][n] = __builtin_amdgcn_mfma_f32_16x16x32_bf16(
                        af[m][kk], bf[n], acc[m][n], 0, 0, 0);
        }

        // col targets for this tile (per-lane column l15)
        int tc[4];
#pragma unroll
        for (int n = 0; n < 4; ++n)
            tc[n] = tgt[cmodb + n * 16 + l15];

        // epilogue: exp, mask, accumulate row sums
#pragma unroll
        for (int m = 0; m < 4; ++m)
#pragma unroll
            for (int n = 0; n < 4; ++n) {
                const int dtest = sdiff + (n - m) * 16;
#pragma unroll
                for (int r = 0; r < 4; ++r) {
                    float e = __builtin_amdgcn_exp2f(acc[m][n][r] * SCALE);
                    fs[m][r] += e;
                    bool excl = (dl == dtest - r) | (tr[m][r] == tc[n]);
                    ns[m][r] += excl ? 0.0f : e;
                }
            }
    }

    // reduce across the 16 column-lanes (same l4 group), then write partials
#pragma unroll
    for (int m = 0; m < 4; ++m)
#pragma unroll
        for (int r = 0; r < 4; ++r) {
            float f = fs[m][r], g = ns[m][r];
#pragma unroll
            for (int msk = 1; msk < 16; msk <<= 1) {
                f += __shfl_xor(f, msk);
                g += __shfl_xor(g, msk);
            }
            if (l15 == 0) {
                int row  = rowbase + m * 16 + l4 * 4 + r;
                int slot = ch * 2 + wc;
                pf[slot * N2 + row]  = f;
                png[slot * N2 + row] = g;
            }
        }
}

// ---- kernel 3: per-row loss + block partial -------------------------------
__global__ __launch_bounds__(256) void row_loss_k(
        const float* __restrict__ pf, const float* __restrict__ png,
        float* __restrict__ bpart)
{
    int row = blockIdx.x * 256 + threadIdx.x;
    float full = 0.f, ng = 0.f;
#pragma unroll
    for (int s = 0; s < 2 * NCH; ++s) {
        full += pf[s * N2 + row];
        ng   += png[s * N2 + row];
    }
    float o1 = full - 0.9f * ng;                // (1 - tau+) = 0.9
    float o2 = full + 818.1f * ng;              // n*tau+ - (1-tau+) = 819 - 0.9
    // per-row loss = -log(o1/o2) = log(o2) - log(o1);  v_log_f32 is log2
    float li = (__builtin_amdgcn_logf(o2) - __builtin_amdgcn_logf(o1)) * 0.6931471805599453f;

#pragma unroll
    for (int m = 1; m < 64; m <<= 1) li += __shfl_xor(li, m);
    __shared__ float red[4];
    if ((threadIdx.x & 63) == 0) red[threadIdx.x >> 6] = li;
    __syncthreads();
    if (threadIdx.x == 0) bpart[blockIdx.x] = red[0] + red[1] + red[2] + red[3];
}

// ---- kernel 4: final scalar ----------------------------------------------
__global__ void final_k(const float* __restrict__ bpart, float* __restrict__ out)
{
    int l = threadIdx.x;
    float v = (l < 32) ? bpart[l] : 0.f;
#pragma unroll
    for (int m = 1; m < 32; m <<= 1) v += __shfl_xor(v, m);
    if (l == 0) out[0] = v / (float)N2;         // mean of per-row losses
}

extern "C" void kernel_launch(void* const* d_in, const int* in_sizes, int n_in,
                              void* d_out, int out_size, void* d_ws, size_t ws_size,
                              hipStream_t stream)
{
    const float* out1 = (const float*)d_in[0];
    const float* out2 = (const float*)d_in[1];
    // d_in[2] = out_m, unused by the loss math
    const int*   tgt  = (const int*)d_in[3];
    float* out = (float*)d_out;

    // workspace layout: bf16 matrix (2MB) | pf (1MB) | png (1MB) | bpart (128B)
    ushort* ob  = (ushort*)d_ws;
    float*  pf  = (float*)((char*)d_ws + (size_t)N2 * DD * 2);
    float*  png = pf + 2 * NCH * N2;
    float*  bpart = png + 2 * NCH * N2;

    convert_k<<<(N2 * DD / 4) / 256, 256, 0, stream>>>(out1, out2, ob);
    dim3 grid(64, NCH);
    simloss_main<<<grid, 256, 0, stream>>>(ob, tgt, pf, png);
    row_loss_k<<<N2 / 256, 256, 0, stream>>>(pf, png, bpart);
    final_k<<<1, 64, 0, stream>>>(bpart, out);
}

// Round 2
// 65.640 us; speedup vs baseline: 1.2272x; 1.2272x over previous
//
#include <hip/hip_runtime.h>
#include <hip/hip_bf16.h>

typedef __attribute__((ext_vector_type(8))) short bf16x8;
typedef __attribute__((ext_vector_type(4))) float f32x4;

constexpr int BQ  = 4096;          // batch per view
constexpr int DD  = 128;           // dim
constexpr int N2  = 2 * BQ;        // 8192
constexpr int NCH = 16;            // column chunks
constexpr int CHW = N2 / NCH;      // 512 cols per block
// exp(s/T) = exp2(s * 2/ln2); pre-scale matrix by sqrt(2.8853900817779268)
constexpr float SQS = 1.6986433f;

static __device__ __forceinline__ ushort f2bf(float f) {
    unsigned u = __builtin_bit_cast(unsigned, f);
    u += 0x7FFFu + ((u >> 16) & 1u);     // round-to-nearest-even
    return (ushort)(u >> 16);
}

// ---- kernel 1: fp32 -> bf16 in MFMA-fragment order, plus mask keys --------
// obF layout: frag(group,kk) at index (group*4+kk)*64+lane, 8 bf16 per lane:
//   lane&15 = row-in-group, lane>>4 = k-octet, so a fragment load is F[base+lane]
//   -> one fully contiguous 1KB load per wave.
__global__ __launch_bounds__(256) void convert_k(const float* __restrict__ a,
        const float* __restrict__ b, const int* __restrict__ tgt,
        ushort* __restrict__ obF, int* __restrict__ key)
{
    int t = blockIdx.x * 256 + threadIdx.x;          // 131072 threads
    int row = t >> 4, c8 = t & 15;
    const float* src = (row < BQ) ? (a + (size_t)row * DD + c8 * 8)
                                  : (b + (size_t)(row - BQ) * DD + c8 * 8);
    float4 v0 = reinterpret_cast<const float4*>(src)[0];
    float4 v1 = reinterpret_cast<const float4*>(src)[1];
    bf16x8 res;
    res[0] = (short)f2bf(v0.x * SQS); res[1] = (short)f2bf(v0.y * SQS);
    res[2] = (short)f2bf(v0.z * SQS); res[3] = (short)f2bf(v0.w * SQS);
    res[4] = (short)f2bf(v1.x * SQS); res[5] = (short)f2bf(v1.y * SQS);
    res[6] = (short)f2bf(v1.z * SQS); res[7] = (short)f2bf(v1.w * SQS);
    int frag = ((row >> 4) * 4 + (c8 >> 2)) * 64 + (c8 & 3) * 16 + (row & 15);
    *reinterpret_cast<bf16x8*>(obF + (size_t)frag * 8) = res;

    if (t < N2) {
        // excl(i,j) == (key[i]==key[j]) covers BOTH the pair mask and target mask:
        // rowmod==colmod implies identical target, so keys collapse correctly.
        int tv = tgt[t & (BQ - 1)];
        key[t] = (tv == -1) ? (0x40000000 + (t & (BQ - 1))) : tv;
    }
}

static __device__ __forceinline__ void ldfrag(const bf16x8* __restrict__ F,
        int la, int lb, int kk, bf16x8 a[2], bf16x8 b[4])
{
    a[0] = F[la + kk * 64];
    a[1] = F[la + kk * 64 + 256];
    b[0] = F[lb + kk * 64];
    b[1] = F[lb + kk * 64 + 256];
    b[2] = F[lb + kk * 64 + 512];
    b[3] = F[lb + kk * 64 + 768];
}

static __device__ __forceinline__ void mfma8(const bf16x8 a[2], const bf16x8 b[4],
                                             f32x4 acc[2][4])
{
#pragma unroll
    for (int m = 0; m < 2; ++m)
#pragma unroll
        for (int n = 0; n < 4; ++n)
            acc[m][n] = __builtin_amdgcn_mfma_f32_16x16x32_bf16(a[m], b[n], acc[m][n], 0, 0, 0);
}

// ---- kernel 2: fused Gram + exp + mask + row sums --------------------------
// 512 thr = 8 waves (4 row x 2 col); wave tile 32x64 per ct; block 128x512.
__global__ __launch_bounds__(512, 4) void simloss_main(
        const ushort* __restrict__ obF, const int* __restrict__ key,
        float* __restrict__ pf, float* __restrict__ png)
{
    const int lane = threadIdx.x & 63;
    const int wid  = threadIdx.x >> 6;
    const int wr   = wid >> 1;            // 0..3
    const int wc   = wid & 1;             // 0..1
    const int l15  = lane & 15;
    const int l4   = lane >> 4;
    const int rowbase = blockIdx.x * 128 + wr * 32;
    const int ch   = blockIdx.y;

    const bf16x8* F = reinterpret_cast<const bf16x8*>(obF);
    const int la = (rowbase >> 4) * 256 + lane;

    // row keys: row = rowbase + m*16 + l4*4 + r  (16 lanes broadcast each)
    int rk[2][4];
#pragma unroll
    for (int m = 0; m < 2; ++m)
#pragma unroll
        for (int r = 0; r < 4; ++r)
            rk[m][r] = key[rowbase + m * 16 + l4 * 4 + r];

    float fs[2][4] = {};
    float ns[2][4] = {};

#pragma unroll 1
    for (int ct = 0; ct < CHW / 128; ++ct) {
        const int cb = ch * CHW + ct * 128 + wc * 64;
        const int lb = (cb >> 4) * 256 + lane;

        int ck[4];
#pragma unroll
        for (int n = 0; n < 4; ++n) ck[n] = key[cb + n * 16 + l15];

        f32x4 acc[2][4] = {};
        bf16x8 aA[2], bA[4], aB[2], bB[4];
        ldfrag(F, la, lb, 0, aA, bA);     // kk=0
        ldfrag(F, la, lb, 1, aB, bB);     // kk=1 in flight
        mfma8(aA, bA, acc);
        ldfrag(F, la, lb, 2, aA, bA);     // kk=2 in flight
        mfma8(aB, bB, acc);
        ldfrag(F, la, lb, 3, aB, bB);     // kk=3 in flight
        mfma8(aA, bA, acc);
        mfma8(aB, bB, acc);

        // epilogue: acc already scaled -> exp2 directly; single-compare mask
#pragma unroll
        for (int m = 0; m < 2; ++m)
#pragma unroll
            for (int n = 0; n < 4; ++n)
#pragma unroll
                for (int r = 0; r < 4; ++r) {
                    float e = __builtin_amdgcn_exp2f(acc[m][n][r]);
                    fs[m][r] += e;
                    ns[m][r] += (rk[m][r] == ck[n]) ? 0.0f : e;
                }
    }

    // reduce across the 16 column-lanes, write per-(chunk,wc) partials
#pragma unroll
    for (int m = 0; m < 2; ++m)
#pragma unroll
        for (int r = 0; r < 4; ++r) {
            float f = fs[m][r], g = ns[m][r];
#pragma unroll
            for (int msk = 1; msk < 16; msk <<= 1) {
                f += __shfl_xor(f, msk);
                g += __shfl_xor(g, msk);
            }
            if (l15 == 0) {
                int row  = rowbase + m * 16 + l4 * 4 + r;
                int slot = ch * 2 + wc;
                pf[slot * N2 + row]  = f;
                png[slot * N2 + row] = g;
            }
        }
}

// ---- kernel 3: per-row loss + block partial -------------------------------
__global__ __launch_bounds__(256) void row_loss_k(
        const float* __restrict__ pf, const float* __restrict__ png,
        float* __restrict__ bpart)
{
    int row = blockIdx.x * 256 + threadIdx.x;
    float full = 0.f, ng = 0.f;
#pragma unroll
    for (int s = 0; s < 2 * NCH; ++s) {
        full += pf[s * N2 + row];
        ng   += png[s * N2 + row];
    }
    float o1 = full - 0.9f * ng;                // (1 - tau+) = 0.9
    float o2 = full + 818.1f * ng;              // n*tau+ - (1-tau+) = 819 - 0.9
    float li = (__builtin_amdgcn_logf(o2) - __builtin_amdgcn_logf(o1)) * 0.6931471805599453f;

#pragma unroll
    for (int m = 1; m < 64; m <<= 1) li += __shfl_xor(li, m);
    __shared__ float red[4];
    if ((threadIdx.x & 63) == 0) red[threadIdx.x >> 6] = li;
    __syncthreads();
    if (threadIdx.x == 0) bpart[blockIdx.x] = red[0] + red[1] + red[2] + red[3];
}

// ---- kernel 4: final scalar ----------------------------------------------
__global__ void final_k(const float* __restrict__ bpart, float* __restrict__ out)
{
    int l = threadIdx.x;
    float v = (l < 32) ? bpart[l] : 0.f;
#pragma unroll
    for (int m = 1; m < 32; m <<= 1) v += __shfl_xor(v, m);
    if (l == 0) out[0] = v / (float)N2;
}

extern "C" void kernel_launch(void* const* d_in, const int* in_sizes, int n_in,
                              void* d_out, int out_size, void* d_ws, size_t ws_size,
                              hipStream_t stream)
{
    const float* out1 = (const float*)d_in[0];
    const float* out2 = (const float*)d_in[1];
    // d_in[2] = out_m, unused by the loss math
    const int*   tgt  = (const int*)d_in[3];
    float* out = (float*)d_out;

    // ws: obF 2MB | pf 1MB | png 1MB | key 32KB | bpart 128B
    ushort* obF  = (ushort*)d_ws;
    float*  pf   = (float*)((char*)d_ws + (2u << 20));
    float*  png  = (float*)((char*)d_ws + (3u << 20));
    int*    key  = (int*)  ((char*)d_ws + (4u << 20));
    float*  bpart= (float*)((char*)d_ws + (4u << 20) + N2 * 4);

    convert_k<<<(N2 * DD / 8) / 256, 256, 0, stream>>>(out1, out2, tgt, obF, key);
    dim3 grid(64, NCH);
    simloss_main<<<grid, 512, 0, stream>>>(obF, key, pf, png);
    row_loss_k<<<N2 / 256, 256, 0, stream>>>(pf, png, bpart);
    final_k<<<1, 64, 0, stream>>>(bpart, out);
}